// Round 5
// baseline (56.010 us; speedup 1.0000x reference)
//
#include <hip/hip_runtime.h>
#include <math.h>

// Diversity8: loss = mean_b( 0.3 * 0.5 * sum_{m!=n} corr(p_m[b], p_n[b]) )
// Key algebra: corr is scale-invariant -> softmax 1/S cancels. With
// u_m[c] = exp(x_m[c]/T) - 1:  cov_mn = <u_m,u_n> - t_m t_n / C,
// corr_mn = cov_mn / sqrt(cov_mm cov_nn).
// So each lane accumulates 36 Gram partials + 8 sums with NO cross-lane
// reductions until one final batch of 44 independent shuffle trees.

constexpr int NC   = 1000;
constexpr int NC4  = 250;     // float4 chunks per row
constexpr int NM   = 8;
constexpr int NPAIR = NM * (NM + 1) / 2;   // 36 (m<=n)
// exp(x/20) = exp2(x * K), K = log2(e)/20
__device__ constexpr float KEXP = 0.072134752044448169f;

__device__ __forceinline__ float waveSum(float v) {
#pragma unroll
    for (int o = 32; o > 0; o >>= 1) v += __shfl_xor(v, o, 64);
    return v;
}
__device__ __forceinline__ double waveSumD(double v) {
#pragma unroll
    for (int o = 32; o > 0; o >>= 1) v += __shfl_xor(v, o, 64);
    return v;
}
// triangular index for m<=n, NM=8; constant-folds under full unroll
__device__ __forceinline__ constexpr int tidx(int m, int n) {
    return m * (2 * NM - m + 1) / 2 + (n - m);
}

__global__ __launch_bounds__(256, 4) void div8_main(
    const float* __restrict__ in0, const float* __restrict__ in1,
    const float* __restrict__ in2, const float* __restrict__ in3,
    const float* __restrict__ in4, const float* __restrict__ in5,
    const float* __restrict__ in6, const float* __restrict__ in7,
    float* __restrict__ part, int B)
{
    const int wid  = threadIdx.x >> 6;
    const int lane = threadIdx.x & 63;
    const int b    = blockIdx.x * 4 + wid;   // one wave per sample
    if (b >= B) return;
    const bool act3 = lane < (NC4 - 3 * 64); // lane < 58: chunk j=3 valid

    const float* rows[NM] = {
        in0 + (size_t)b * NC, in1 + (size_t)b * NC,
        in2 + (size_t)b * NC, in3 + (size_t)b * NC,
        in4 + (size_t)b * NC, in5 + (size_t)b * NC,
        in6 + (size_t)b * NC, in7 + (size_t)b * NC };

    float D[NPAIR];            // sum_c u_m u_n  (m<=n)
    float t[NM];               // sum_c u_m
#pragma unroll
    for (int k = 0; k < NPAIR; ++k) D[k] = 0.f;
#pragma unroll
    for (int m = 0; m < NM; ++m) t[m] = 0.f;

#pragma unroll
    for (int j = 0; j < 4; ++j) {
        // load this chunk for all 8 models (8 coalesced float4 loads in flight)
        float4 u[NM];
#pragma unroll
        for (int m = 0; m < NM; ++m) {
            const float4* p = reinterpret_cast<const float4*>(rows[m]);
            if (j < 3) {
                float4 v = p[lane + 64 * j];
                u[m].x = exp2f(v.x * KEXP) - 1.f;
                u[m].y = exp2f(v.y * KEXP) - 1.f;
                u[m].z = exp2f(v.z * KEXP) - 1.f;
                u[m].w = exp2f(v.w * KEXP) - 1.f;
            } else if (act3) {
                float4 v = p[lane + 192];
                u[m].x = exp2f(v.x * KEXP) - 1.f;
                u[m].y = exp2f(v.y * KEXP) - 1.f;
                u[m].z = exp2f(v.z * KEXP) - 1.f;
                u[m].w = exp2f(v.w * KEXP) - 1.f;
            } else {
                u[m] = make_float4(0.f, 0.f, 0.f, 0.f);  // pads: contribute nothing
            }
        }
        // accumulate 44 partials per scalar component
#pragma unroll
        for (int comp = 0; comp < 4; ++comp) {
            float us[NM];
#pragma unroll
            for (int m = 0; m < NM; ++m)
                us[m] = (comp == 0) ? u[m].x : (comp == 1) ? u[m].y
                      : (comp == 2) ? u[m].z : u[m].w;
#pragma unroll
            for (int m = 0; m < NM; ++m) {
                t[m] += us[m];
#pragma unroll
                for (int n = m; n < NM; ++n)
                    D[tidx(m, n)] = fmaf(us[m], us[n], D[tidx(m, n)]);
            }
        }
    }

    // ---- one batch of 44 independent wave reductions (chains pipeline) ----
#pragma unroll
    for (int k = 0; k < NPAIR; ++k) D[k] = waveSum(D[k]);
#pragma unroll
    for (int m = 0; m < NM; ++m) t[m] = waveSum(t[m]);

    // ---- epilogue: 8x8 pair combination in f64 ----
    if (lane == 0) {
        constexpr double INVC_D = 1.0 / (double)NC;
        double rm[NM];
#pragma unroll
        for (int m = 0; m < NM; ++m) {
            double q = (double)D[tidx(m, m)] - (double)t[m] * (double)t[m] * INVC_D;
            rm[m] = 1.0 / sqrt(q);
        }
        double cr = 0.0;
#pragma unroll
        for (int m = 0; m < NM; ++m)
#pragma unroll
            for (int n = m + 1; n < NM; ++n) {
                double cov = (double)D[tidx(m, n)]
                           - (double)t[m] * (double)t[n] * INVC_D;
                cr += cov * rm[m] * rm[n];
            }
        part[b] = (float)(2.0 * cr);   // = sum_{m!=n} corr_mn for sample b
    }
}

__global__ __launch_bounds__(256) void div8_final(
    const float* __restrict__ part, float* __restrict__ out, int B)
{
    const int t = threadIdx.x;
    double acc = 0.0;
    for (int i = t; i < B; i += 256) acc += (double)part[i];  // fixed order: deterministic
    acc = waveSumD(acc);
    __shared__ double redd[4];
    if ((t & 63) == 0) redd[t >> 6] = acc;
    __syncthreads();
    if (t == 0) {
        double tot = (redd[0] + redd[1]) + (redd[2] + redd[3]);
        // loss = mean( 0.3 * 0.5 * cross_b )
        out[0] = (float)(tot * (0.5 * 0.3 / (double)B));
    }
}

extern "C" void kernel_launch(void* const* d_in, const int* in_sizes, int n_in,
                              void* d_out, int out_size, void* d_ws, size_t ws_size,
                              hipStream_t stream)
{
    const float* a0 = (const float*)d_in[0];
    const float* a1 = (const float*)d_in[1];
    const float* a2 = (const float*)d_in[2];
    const float* a3 = (const float*)d_in[3];
    const float* a4 = (const float*)d_in[4];
    const float* a5 = (const float*)d_in[5];
    const float* a6 = (const float*)d_in[6];
    const float* a7 = (const float*)d_in[7];
    const int B = in_sizes[0] / NC;   // 4096

    float* part = (float*)d_ws;       // B floats of scratch

    const int grid = (B + 3) / 4;     // 4 samples (waves) per block
    div8_main<<<grid, 256, 0, stream>>>(a0, a1, a2, a3, a4, a5, a6, a7, part, B);
    div8_final<<<1, 256, 0, stream>>>(part, (float*)d_out, B);
}

// Round 6
// 45.936 us; speedup vs baseline: 1.2193x; 1.2193x over previous
//
#include <hip/hip_runtime.h>
#include <math.h>

// Diversity8: loss = mean_b( 0.3 * 0.5 * sum_{m!=n} corr(p_m[b], p_n[b]) )
// corr is scale/shift-invariant -> softmax 1/S cancels. With
// u_m[c] = exp(x_m[c]/T) - 1 (the -1 keeps Gram terms small: no cancellation):
//   cov_mn = <u_m,u_n> - t_m t_n / C,  corr_mn = cov_mn / sqrt(cov_mm cov_nn)
// Each lane accumulates 36 Gram partials + 8 sums (NO cross-lane traffic),
// then ONE batch of 44 independent butterfly reductions; epilogue runs
// redundantly on all lanes (values are broadcast by the butterfly).
// R5 lesson: __launch_bounds__(256,4) capped VGPR=64 -> spill (+24MB fetch).
// Plain (256) lets the allocator take ~130 regs, zero scratch.

constexpr int NC    = 1000;
constexpr int NC4   = 250;     // float4 chunks per row
constexpr int NM    = 8;
constexpr int NPAIR = NM * (NM + 1) / 2;   // 36 (m<=n)
constexpr float KEXP = 0.072134752044448169f;  // log2(e)/20:  exp(x/20)=exp2(x*KEXP)
constexpr float INVC = 1.0f / (float)NC;

__device__ __forceinline__ float waveSum(float v) {
#pragma unroll
    for (int o = 32; o > 0; o >>= 1) v += __shfl_xor(v, o, 64);
    return v;
}
__device__ __forceinline__ double waveSumD(double v) {
#pragma unroll
    for (int o = 32; o > 0; o >>= 1) v += __shfl_xor(v, o, 64);
    return v;
}
// triangular index for m<=n, NM=8; constant-folds under full unroll
__device__ __forceinline__ constexpr int tidx(int m, int n) {
    return m * (2 * NM - m + 1) / 2 + (n - m);
}

__global__ __launch_bounds__(256) void div8_main(
    const float* __restrict__ in0, const float* __restrict__ in1,
    const float* __restrict__ in2, const float* __restrict__ in3,
    const float* __restrict__ in4, const float* __restrict__ in5,
    const float* __restrict__ in6, const float* __restrict__ in7,
    float* __restrict__ part, int B)
{
    const int wid  = threadIdx.x >> 6;
    const int lane = threadIdx.x & 63;
    const int b    = blockIdx.x * 4 + wid;   // one wave per sample
    if (b >= B) return;
    const bool act3 = lane < (NC4 - 3 * 64); // lane < 58: chunk j=3 valid

    const float* rows[NM] = {
        in0 + (size_t)b * NC, in1 + (size_t)b * NC,
        in2 + (size_t)b * NC, in3 + (size_t)b * NC,
        in4 + (size_t)b * NC, in5 + (size_t)b * NC,
        in6 + (size_t)b * NC, in7 + (size_t)b * NC };

    float D[NPAIR];            // sum_c u_m u_n  (m<=n)
    float t[NM];               // sum_c u_m
#pragma unroll
    for (int k = 0; k < NPAIR; ++k) D[k] = 0.f;
#pragma unroll
    for (int m = 0; m < NM; ++m) t[m] = 0.f;

#pragma unroll
    for (int j = 0; j < 4; ++j) {
        // load this chunk for all 8 models (8 coalesced 1KB-per-wave loads)
        float4 u[NM];
#pragma unroll
        for (int m = 0; m < NM; ++m) {
            const float4* p = reinterpret_cast<const float4*>(rows[m]);
            if (j < 3 || act3) {
                float4 v = p[lane + 64 * j];
                u[m].x = exp2f(v.x * KEXP) - 1.f;
                u[m].y = exp2f(v.y * KEXP) - 1.f;
                u[m].z = exp2f(v.z * KEXP) - 1.f;
                u[m].w = exp2f(v.w * KEXP) - 1.f;
            } else {
                u[m] = make_float4(0.f, 0.f, 0.f, 0.f);  // pads: contribute nothing
            }
        }
        // accumulate 44 partials per scalar component (all static indexing)
#pragma unroll
        for (int comp = 0; comp < 4; ++comp) {
            float us[NM];
#pragma unroll
            for (int m = 0; m < NM; ++m)
                us[m] = (comp == 0) ? u[m].x : (comp == 1) ? u[m].y
                      : (comp == 2) ? u[m].z : u[m].w;
#pragma unroll
            for (int m = 0; m < NM; ++m) {
                t[m] += us[m];
#pragma unroll
                for (int n = m; n < NM; ++n)
                    D[tidx(m, n)] = fmaf(us[m], us[n], D[tidx(m, n)]);
            }
        }
    }

    // ---- one batch of 44 independent butterfly reductions; results are
    //      broadcast into every lane ----
#pragma unroll
    for (int k = 0; k < NPAIR; ++k) D[k] = waveSum(D[k]);
#pragma unroll
    for (int m = 0; m < NM; ++m) t[m] = waveSum(t[m]);

    // ---- epilogue, computed redundantly on all 64 lanes (no serial stall) --
    float rm[NM];
#pragma unroll
    for (int m = 0; m < NM; ++m) {
        // q = cov_mm: D_mm ~ 2.5, correction ~ 0.0016 -> no cancellation
        float q = fmaf(-t[m] * INVC, t[m], D[tidx(m, m)]);
        rm[m] = 1.0f / sqrtf(q);
    }
    double cr = 0.0;
#pragma unroll
    for (int m = 0; m < NM; ++m)
#pragma unroll
        for (int n = m + 1; n < NM; ++n) {
            float cov = fmaf(-t[m] * INVC, t[n], D[tidx(m, n)]);
            cr += (double)(cov * rm[m] * rm[n]);
        }
    if (lane == 0) part[b] = (float)(2.0 * cr);  // = sum_{m!=n} corr_mn
}

__global__ __launch_bounds__(256) void div8_final(
    const float* __restrict__ part, float* __restrict__ out, int B)
{
    const int t = threadIdx.x;
    double acc = 0.0;
    for (int i = t; i < B; i += 256) acc += (double)part[i];  // fixed order: deterministic
    acc = waveSumD(acc);
    __shared__ double redd[4];
    if ((t & 63) == 0) redd[t >> 6] = acc;
    __syncthreads();
    if (t == 0) {
        double tot = (redd[0] + redd[1]) + (redd[2] + redd[3]);
        // loss = mean( 0.3 * 0.5 * cross_b )
        out[0] = (float)(tot * (0.5 * 0.3 / (double)B));
    }
}

extern "C" void kernel_launch(void* const* d_in, const int* in_sizes, int n_in,
                              void* d_out, int out_size, void* d_ws, size_t ws_size,
                              hipStream_t stream)
{
    const float* a0 = (const float*)d_in[0];
    const float* a1 = (const float*)d_in[1];
    const float* a2 = (const float*)d_in[2];
    const float* a3 = (const float*)d_in[3];
    const float* a4 = (const float*)d_in[4];
    const float* a5 = (const float*)d_in[5];
    const float* a6 = (const float*)d_in[6];
    const float* a7 = (const float*)d_in[7];
    const int B = in_sizes[0] / NC;   // 4096

    float* part = (float*)d_ws;       // B floats of scratch

    const int grid = (B + 3) / 4;     // 4 samples (waves) per block
    div8_main<<<grid, 256, 0, stream>>>(a0, a1, a2, a3, a4, a5, a6, a7, part, B);
    div8_final<<<1, 256, 0, stream>>>(part, (float*)d_out, B);
}

// Round 7
// 38.409 us; speedup vs baseline: 1.4582x; 1.1960x over previous
//
#include <hip/hip_runtime.h>
#include <math.h>

// Diversity8: loss = mean_b( 0.3 * 0.5 * sum_{m!=n} corr(p_m[b], p_n[b]) )
// corr is scale/shift-invariant -> softmax 1/S cancels. With
// u_m[c] = exp(x_m[c]/T) - 1:  cov_mn = <u_m,u_n> - t_m t_n / C,
// corr_mn = cov_mn / sqrt(cov_mm cov_nn).
// Lane-local: 36 Gram partials + 8 sums, zero cross-lane traffic until one
// batch of 44 independent butterflies. One wave per sample, no LDS/barriers.
// R6 lesson: default VGPR budget (84) serializes the 32 chunk loads into ~4
// HBM round trips. Fix: double-buffered chunk pipeline + launch_bounds(256,2)
// to unlock ~128 VGPRs (R5 showed (256,4)->cap 64 = spill; (256,2) is safe
// under both plausible semantics: cap 128 or 256).

constexpr int NC    = 1000;
constexpr int NC4   = 250;     // float4 chunks per row
constexpr int NM    = 8;
constexpr int NPAIR = NM * (NM + 1) / 2;   // 36 (m<=n)
constexpr float KEXP = 0.072134752044448169f;  // log2(e)/20: exp(x/20)=exp2(x*KEXP)
constexpr float INVC = 1.0f / (float)NC;

__device__ __forceinline__ float waveSum(float v) {
#pragma unroll
    for (int o = 32; o > 0; o >>= 1) v += __shfl_xor(v, o, 64);
    return v;
}
__device__ __forceinline__ double waveSumD(double v) {
#pragma unroll
    for (int o = 32; o > 0; o >>= 1) v += __shfl_xor(v, o, 64);
    return v;
}
// triangular index for m<=n, NM=8; constant-folds under full unroll
__device__ __forceinline__ constexpr int tidx(int m, int n) {
    return m * (2 * NM - m + 1) / 2 + (n - m);
}

__global__ __launch_bounds__(256, 2) void div8_main(
    const float* __restrict__ in0, const float* __restrict__ in1,
    const float* __restrict__ in2, const float* __restrict__ in3,
    const float* __restrict__ in4, const float* __restrict__ in5,
    const float* __restrict__ in6, const float* __restrict__ in7,
    float* __restrict__ part, int B)
{
    const int wid  = threadIdx.x >> 6;
    const int lane = threadIdx.x & 63;
    const int b    = blockIdx.x * 4 + wid;   // one wave per sample
    if (b >= B) return;
    const bool act3 = lane < (NC4 - 3 * 64); // lane < 58: chunk j=3 valid

    const float4* p[NM] = {
        reinterpret_cast<const float4*>(in0 + (size_t)b * NC),
        reinterpret_cast<const float4*>(in1 + (size_t)b * NC),
        reinterpret_cast<const float4*>(in2 + (size_t)b * NC),
        reinterpret_cast<const float4*>(in3 + (size_t)b * NC),
        reinterpret_cast<const float4*>(in4 + (size_t)b * NC),
        reinterpret_cast<const float4*>(in5 + (size_t)b * NC),
        reinterpret_cast<const float4*>(in6 + (size_t)b * NC),
        reinterpret_cast<const float4*>(in7 + (size_t)b * NC) };

    // chunk addresses + masks (branch-free pad handling: clamped address)
    const int   idx[4] = { lane, lane + 64, lane + 128, act3 ? lane + 192 : NC4 - 1 };
    const float msk[4] = { 1.f, 1.f, 1.f, act3 ? 1.f : 0.f };

    float D[NPAIR];            // sum_c u_m u_n  (m<=n)
    float t[NM];               // sum_c u_m
#pragma unroll
    for (int k = 0; k < NPAIR; ++k) D[k] = 0.f;
#pragma unroll
    for (int m = 0; m < NM; ++m) t[m] = 0.f;

    // ---- software-pipelined chunk loop: load j+1 while computing j ----
    float4 cur[NM], nxt[NM];
#pragma unroll
    for (int m = 0; m < NM; ++m) cur[m] = p[m][idx[0]];

#pragma unroll
    for (int j = 0; j < 4; ++j) {
        if (j < 3) {
#pragma unroll
            for (int m = 0; m < NM; ++m) nxt[m] = p[m][idx[j + 1]];
        }
        // exp in-place (overwrites cur): u = (exp2(v*K) - 1) * msk
        const float mj = msk[j];
#pragma unroll
        for (int m = 0; m < NM; ++m) {
            cur[m].x = (exp2f(cur[m].x * KEXP) - 1.f) * mj;
            cur[m].y = (exp2f(cur[m].y * KEXP) - 1.f) * mj;
            cur[m].z = (exp2f(cur[m].z * KEXP) - 1.f) * mj;
            cur[m].w = (exp2f(cur[m].w * KEXP) - 1.f) * mj;
        }
        // accumulate 44 partials per scalar component (static indexing only)
#pragma unroll
        for (int comp = 0; comp < 4; ++comp) {
            float us[NM];
#pragma unroll
            for (int m = 0; m < NM; ++m)
                us[m] = (comp == 0) ? cur[m].x : (comp == 1) ? cur[m].y
                      : (comp == 2) ? cur[m].z : cur[m].w;
#pragma unroll
            for (int m = 0; m < NM; ++m) {
                t[m] += us[m];
#pragma unroll
                for (int n = m; n < NM; ++n)
                    D[tidx(m, n)] = fmaf(us[m], us[n], D[tidx(m, n)]);
            }
        }
        if (j < 3) {
#pragma unroll
            for (int m = 0; m < NM; ++m) cur[m] = nxt[m];
        }
    }

    // ---- one batch of 44 independent butterflies (results broadcast) ----
#pragma unroll
    for (int k = 0; k < NPAIR; ++k) D[k] = waveSum(D[k]);
#pragma unroll
    for (int m = 0; m < NM; ++m) t[m] = waveSum(t[m]);

    // ---- epilogue on all 64 lanes (no serial stall); lane 0 stores ----
    float rm[NM];
#pragma unroll
    for (int m = 0; m < NM; ++m) {
        // cov_mm: D_mm ~ 2.5, correction ~ 0.0016 -> no cancellation
        float q = fmaf(-t[m] * INVC, t[m], D[tidx(m, m)]);
        rm[m] = 1.0f / sqrtf(q);
    }
    double cr = 0.0;
#pragma unroll
    for (int m = 0; m < NM; ++m)
#pragma unroll
        for (int n = m + 1; n < NM; ++n) {
            float cov = fmaf(-t[m] * INVC, t[n], D[tidx(m, n)]);
            cr += (double)(cov * rm[m] * rm[n]);
        }
    if (lane == 0) part[b] = (float)(2.0 * cr);  // = sum_{m!=n} corr_mn
}

__global__ __launch_bounds__(256) void div8_final(
    const float* __restrict__ part, float* __restrict__ out, int B)
{
    const int t = threadIdx.x;
    double acc = 0.0;
    for (int i = t; i < B; i += 256) acc += (double)part[i];  // fixed order: deterministic
    acc = waveSumD(acc);
    __shared__ double redd[4];
    if ((t & 63) == 0) redd[t >> 6] = acc;
    __syncthreads();
    if (t == 0) {
        double tot = (redd[0] + redd[1]) + (redd[2] + redd[3]);
        // loss = mean( 0.3 * 0.5 * cross_b )
        out[0] = (float)(tot * (0.5 * 0.3 / (double)B));
    }
}

extern "C" void kernel_launch(void* const* d_in, const int* in_sizes, int n_in,
                              void* d_out, int out_size, void* d_ws, size_t ws_size,
                              hipStream_t stream)
{
    const float* a0 = (const float*)d_in[0];
    const float* a1 = (const float*)d_in[1];
    const float* a2 = (const float*)d_in[2];
    const float* a3 = (const float*)d_in[3];
    const float* a4 = (const float*)d_in[4];
    const float* a5 = (const float*)d_in[5];
    const float* a6 = (const float*)d_in[6];
    const float* a7 = (const float*)d_in[7];
    const int B = in_sizes[0] / NC;   // 4096

    float* part = (float*)d_ws;       // B floats of scratch

    const int grid = (B + 3) / 4;     // 4 samples (waves) per block
    div8_main<<<grid, 256, 0, stream>>>(a0, a1, a2, a3, a4, a5, a6, a7, part, B);
    div8_final<<<1, 256, 0, stream>>>(part, (float*)d_out, B);
}